// Round 3
// baseline (772.423 us; speedup 1.0000x reference)
//
#include <hip/hip_runtime.h>

typedef unsigned short u16;
typedef __bf16 bf16x8 __attribute__((ext_vector_type(8)));
typedef float f32x4 __attribute__((ext_vector_type(4)));

#define BS_TOT 32768   // B*S
#define SS 4096
#define DD 1024
#define MM 32

__device__ __forceinline__ float bf2f(u16 u) {
    union { float f; unsigned int i; } c; c.i = ((unsigned int)u) << 16; return c.f;
}
__device__ __forceinline__ u16 f2bf(float f) {
    union { float f; unsigned int i; } c; c.f = f;
    unsigned int r = c.i + 0x7FFFu + ((c.i >> 16) & 1u);
    return (u16)(r >> 16);
}
__device__ __forceinline__ f32x4 mfma16(bf16x8 a, bf16x8 b, f32x4 c) {
    return __builtin_amdgcn_mfma_f32_16x16x32_bf16(a, b, c, 0, 0, 0);
}
// read element i of an input tensor that is either bf16 (f32m=0) or f32 (f32m=1)
__device__ __forceinline__ u16 cvt_in(const void* p, size_t i, int f32m) {
    return f32m ? f2bf(((const float*)p)[i]) : ((const u16*)p)[i];
}
// pack 8 f32 -> 8 bf16 in a uint4
__device__ __forceinline__ uint4 pack8(float4 a, float4 b) {
    uint4 v;
    v.x = (unsigned)f2bf(a.x) | ((unsigned)f2bf(a.y) << 16);
    v.y = (unsigned)f2bf(a.z) | ((unsigned)f2bf(a.w) << 16);
    v.z = (unsigned)f2bf(b.x) | ((unsigned)f2bf(b.y) << 16);
    v.w = (unsigned)f2bf(b.z) | ((unsigned)f2bf(b.w) << 16);
    return v;
}

// ---------------------------------------------------------------------------
// K-1: dtype detector (insurance; round-1/2 evidence says inputs are f32).
// For f32 N(0,1) data, the low-u16's bits 14..7 are uniform mantissa bits
// (~10% in [110,135]); for bf16-pair data they're a bf16 exponent (~99.9%).
// flag=1 -> inputs are f32.
// ---------------------------------------------------------------------------
__global__ __launch_bounds__(64) void zej_detect(const unsigned int* __restrict__ xw,
                                                 int* __restrict__ flag)
{
    int lane = threadIdx.x;
    int cnt = 0;
#pragma unroll
    for (int i = 0; i < 16; i++) {
        unsigned int w = xw[lane * 16 + i];
        unsigned int e = (w >> 7) & 0xFFu;
        cnt += (e >= 110u && e <= 135u) ? 1 : 0;
    }
#pragma unroll
    for (int off = 32; off > 0; off >>= 1) cnt += __shfl_down(cnt, off);
    if (lane == 0) *flag = (cnt < 512) ? 1 : 0;
}

// ---------------------------------------------------------------------------
// K0: pack/transpose weights + biases into bf16 n-major layouts in ws.
//   W3T[96][1024] = [Wr|Ww|Wm]^T,  WpT[1024][32] = Wp^T,  WoT[1024][2048] = Wo^T
//   biasp: [0:96]=br|bw|bm, [96:1120]=bp, [1120:2144]=bo
// ---------------------------------------------------------------------------
__global__ __launch_bounds__(256) void zej_pack(
    const void* __restrict__ Wr, const void* __restrict__ Ww, const void* __restrict__ Wm,
    const void* __restrict__ Wp, const void* __restrict__ Wo,
    const void* __restrict__ br, const void* __restrict__ bw, const void* __restrict__ bm,
    const void* __restrict__ bp, const void* __restrict__ bo,
    u16* __restrict__ W3T, u16* __restrict__ WpT, u16* __restrict__ WoT,
    u16* __restrict__ biasp, const int* __restrict__ flag)
{
    const int f32m = *flag;
    int i = blockIdx.x * 256 + threadIdx.x;
    if (i < 98304) {            // W3T
        int j = i >> 10, k = i & 1023;
        W3T[i] = (j < 32) ? cvt_in(Wr, (size_t)k * 32 + j, f32m)
               : (j < 64) ? cvt_in(Ww, (size_t)k * 32 + (j - 32), f32m)
                          : cvt_in(Wm, (size_t)k * 32 + (j - 64), f32m);
        return;
    }
    i -= 98304;
    if (i < 32768) {            // WpT
        int n = i >> 5, k = i & 31;
        WpT[i] = cvt_in(Wp, (size_t)k * 1024 + n, f32m);
        return;
    }
    i -= 32768;
    if (i < 2097152) {          // WoT
        int n = i >> 11, k = i & 2047;
        WoT[i] = cvt_in(Wo, (size_t)k * 1024 + n, f32m);
        return;
    }
    i -= 2097152;
    if (i < 96) {
        biasp[i] = (i < 32) ? cvt_in(br, i, f32m)
                 : (i < 64) ? cvt_in(bw, i - 32, f32m)
                            : cvt_in(bm, i - 64, f32m);
        return;
    }
    i -= 96;
    if (i < 1024) { biasp[96 + i] = cvt_in(bp, i, f32m); return; }
    i -= 1024;
    if (i < 1024) { biasp[1120 + i] = cvt_in(bo, i, f32m); }
}

// ---------------------------------------------------------------------------
// K1: gates = x @ [Wr|Ww|Wm] (+bias, sigmoid on cols<64).  32768x1024 @ 1024x96.
// ---------------------------------------------------------------------------
__global__ __launch_bounds__(256) void zej_gates(
    const void* __restrict__ x, const u16* __restrict__ W3T,
    const u16* __restrict__ biasp, u16* __restrict__ gates,
    const int* __restrict__ flag)
{
    __shared__ __align__(16) u16 As[128][88];
    __shared__ __align__(16) u16 Bs[96][88];
    const int f32m = *flag;
    const int t = threadIdx.x;
    const int lane = t & 63;
    const int wv = t >> 6;
    const int row0 = blockIdx.x * 128;
    const int lm = lane & 15, lq = lane >> 4;

    f32x4 acc[2][6];
    f32x4 z = {0.f, 0.f, 0.f, 0.f};
#pragma unroll
    for (int i = 0; i < 2; i++)
#pragma unroll
        for (int j = 0; j < 6; j++) acc[i][j] = z;

    for (int k0 = 0; k0 < 1024; k0 += 64) {
#pragma unroll
        for (int c = 0; c < 4; c++) {            // A: 128x64
            int chunk = t + c * 256;
            int r = chunk >> 3, kc = (chunk & 7) * 8;
            size_t gi = (size_t)(row0 + r) * 1024 + k0 + kc;
            if (f32m) {
                const float* xf = (const float*)x;
                float4 f0 = *(const float4*)(xf + gi);
                float4 f1 = *(const float4*)(xf + gi + 4);
                *(uint4*)&As[r][kc] = pack8(f0, f1);
            } else {
                *(uint4*)&As[r][kc] = *(const uint4*)((const u16*)x + gi);
            }
        }
#pragma unroll
        for (int c = 0; c < 3; c++) {            // B: 96x64
            int chunk = t + c * 256;
            int j = chunk >> 3, kc = (chunk & 7) * 8;
            *(uint4*)&Bs[j][kc] = *(const uint4*)&W3T[j * 1024 + k0 + kc];
        }
        __syncthreads();
#pragma unroll
        for (int ks = 0; ks < 2; ks++) {
            int kk = ks * 32 + lq * 8;
            bf16x8 a[2], b[6];
#pragma unroll
            for (int rt = 0; rt < 2; rt++) a[rt] = *(const bf16x8*)&As[wv * 32 + rt * 16 + lm][kk];
#pragma unroll
            for (int ct = 0; ct < 6; ct++) b[ct] = *(const bf16x8*)&Bs[ct * 16 + lm][kk];
#pragma unroll
            for (int rt = 0; rt < 2; rt++)
#pragma unroll
                for (int ct = 0; ct < 6; ct++)
                    acc[rt][ct] = mfma16(a[rt], b[ct], acc[rt][ct]);
        }
        __syncthreads();
    }
#pragma unroll
    for (int rt = 0; rt < 2; rt++) {
#pragma unroll
        for (int ct = 0; ct < 6; ct++) {
            int col = ct * 16 + lm;
            float bias = bf2f(biasp[col]);
            bool sig = (col < 64);
#pragma unroll
            for (int p = 0; p < 4; p++) {
                int R = row0 + wv * 32 + rt * 16 + lq * 4 + p;
                float v = acc[rt][ct][p] + bias;
                if (sig) v = 1.f / (1.f + __expf(-v));
                gates[R * 96 + col] = f2bf(v);
            }
        }
    }
}

// ---------------------------------------------------------------------------
// K2: per-channel linear-recurrence scan.  One wave per (b,m) channel.
// mem_{t+1} = (1-w)*mem + w*nm;  emit rm_t = r_t*mem_t (mem BEFORE update).
// ---------------------------------------------------------------------------
__global__ __launch_bounds__(64) void zej_scan(
    const u16* __restrict__ gates, u16* __restrict__ rm)
{
    const int c = blockIdx.x;       // 0..255
    const int b = c >> 5;
    const int m = c & 31;
    const int lane = threadIdx.x;
    const u16* gb = gates + (size_t)b * SS * 96;
    const int tbase = lane * 64;

    float A = 1.f, Bc = 0.f;
    for (int i = 0; i < 64; i++) {
        int idx = (tbase + i) * 96;
        float w = bf2f(gb[idx + 32 + m]);
        float nm = bf2f(gb[idx + 64 + m]);
        float a = 1.f - w;
        Bc = a * Bc + w * nm;
        A *= a;
    }
    for (int off = 1; off < 64; off <<= 1) {
        float Ap = __shfl_up(A, off);
        float Bp = __shfl_up(Bc, off);
        if (lane >= off) { Bc = A * Bp + Bc; A = A * Ap; }
    }
    float Bprev = __shfl_up(Bc, 1);
    float mem = (lane == 0) ? 0.f : Bprev;

    for (int i = 0; i < 64; i++) {
        int idx = (tbase + i) * 96;
        float r = bf2f(gb[idx + m]);
        float w = bf2f(gb[idx + 32 + m]);
        float nm = bf2f(gb[idx + 64 + m]);
        rm[((size_t)b * SS + tbase + i) * 32 + m] = f2bf(r * mem);
        mem = (1.f - w) * mem + w * nm;
    }
}

// ---------------------------------------------------------------------------
// K3: q = rm @ Wp + bp.  32768x32 @ 32x1024.  One MFMA per 16x16 tile.
// ---------------------------------------------------------------------------
__global__ __launch_bounds__(256) void zej_q(
    const u16* __restrict__ rm, const u16* __restrict__ WpT,
    const u16* __restrict__ biasp, u16* __restrict__ q)
{
    __shared__ __align__(16) u16 As[64][40];
    __shared__ __align__(16) u16 Bs[256][40];
    const int t = threadIdx.x;
    const int lane = t & 63;
    const int wv = t >> 6;
    const int row0 = blockIdx.x * 64;
    const int n0 = blockIdx.y * 256;
    const int lm = lane & 15, lq = lane >> 4;

    { int r = t >> 2, kc = (t & 3) * 8;
      *(uint4*)&As[r][kc] = *(const uint4*)&rm[(size_t)(row0 + r) * 32 + kc]; }
#pragma unroll
    for (int cc = 0; cc < 4; cc++) {
        int chunk = t + cc * 256;
        int n = chunk >> 2, kc = (chunk & 3) * 8;
        *(uint4*)&Bs[n][kc] = *(const uint4*)&WpT[(size_t)(n0 + n) * 32 + kc];
    }
    __syncthreads();

    const int kk = lq * 8;
    bf16x8 a[4], b[4];
#pragma unroll
    for (int rt = 0; rt < 4; rt++) a[rt] = *(const bf16x8*)&As[rt * 16 + lm][kk];
#pragma unroll
    for (int ct = 0; ct < 4; ct++) b[ct] = *(const bf16x8*)&Bs[wv * 64 + ct * 16 + lm][kk];

    f32x4 z = {0.f, 0.f, 0.f, 0.f};
#pragma unroll
    for (int rt = 0; rt < 4; rt++) {
#pragma unroll
        for (int ct = 0; ct < 4; ct++) {
            f32x4 acc = mfma16(a[rt], b[ct], z);
            int n = n0 + wv * 64 + ct * 16 + lm;
            float bias = bf2f(biasp[96 + n]);
#pragma unroll
            for (int p = 0; p < 4; p++) {
                int R = row0 + rt * 16 + lq * 4 + p;
                q[(size_t)R * 1024 + n] = f2bf(acc[p] + bias);
            }
        }
    }
}

// ---------------------------------------------------------------------------
// K4: out = tanh([x | q] @ Wo + bo).  32768x2048 @ 2048x1024.  f32 OUTPUT.
// ---------------------------------------------------------------------------
__global__ __launch_bounds__(256) void zej_out(
    const void* __restrict__ x, const u16* __restrict__ q,
    const u16* __restrict__ WoT, const u16* __restrict__ biasp,
    float* __restrict__ out, const int* __restrict__ flag)
{
    __shared__ __align__(16) u16 As[128][88];
    __shared__ __align__(16) u16 Bs[128][88];
    const int f32m = *flag;
    const int t = threadIdx.x;
    const int lane = t & 63;
    const int wv = t >> 6;
    const int wr = (wv >> 1) * 64;
    const int wc = (wv & 1) * 64;
    const int row0 = blockIdx.x * 128;
    const int n0 = blockIdx.y * 128;
    const int lm = lane & 15, lq = lane >> 4;

    f32x4 acc[4][4];
    f32x4 z = {0.f, 0.f, 0.f, 0.f};
#pragma unroll
    for (int i = 0; i < 4; i++)
#pragma unroll
        for (int j = 0; j < 4; j++) acc[i][j] = z;

    for (int k0 = 0; k0 < 2048; k0 += 64) {
        const int from_x = (k0 < 1024);
        const int koff = from_x ? k0 : (k0 - 1024);
#pragma unroll
        for (int c = 0; c < 4; c++) {
            int chunk = t + c * 256;
            int r = chunk >> 3, kc = (chunk & 7) * 8;
            size_t gi = (size_t)(row0 + r) * 1024 + koff + kc;
            if (from_x) {
                if (f32m) {
                    const float* xf = (const float*)x;
                    float4 f0 = *(const float4*)(xf + gi);
                    float4 f1 = *(const float4*)(xf + gi + 4);
                    *(uint4*)&As[r][kc] = pack8(f0, f1);
                } else {
                    *(uint4*)&As[r][kc] = *(const uint4*)((const u16*)x + gi);
                }
            } else {
                *(uint4*)&As[r][kc] = *(const uint4*)&q[gi];
            }
            *(uint4*)&Bs[r][kc] = *(const uint4*)&WoT[(size_t)(n0 + r) * 2048 + k0 + kc];
        }
        __syncthreads();
#pragma unroll
        for (int ks = 0; ks < 2; ks++) {
            int kk = ks * 32 + lq * 8;
            bf16x8 a[4], b[4];
#pragma unroll
            for (int rt = 0; rt < 4; rt++) a[rt] = *(const bf16x8*)&As[wr + rt * 16 + lm][kk];
#pragma unroll
            for (int ct = 0; ct < 4; ct++) b[ct] = *(const bf16x8*)&Bs[wc + ct * 16 + lm][kk];
#pragma unroll
            for (int rt = 0; rt < 4; rt++)
#pragma unroll
                for (int ct = 0; ct < 4; ct++)
                    acc[rt][ct] = mfma16(a[rt], b[ct], acc[rt][ct]);
        }
        __syncthreads();
    }
#pragma unroll
    for (int rt = 0; rt < 4; rt++) {
#pragma unroll
        for (int ct = 0; ct < 4; ct++) {
            int n = n0 + wc + ct * 16 + lm;
            float bias = bf2f(biasp[1120 + n]);
#pragma unroll
            for (int p = 0; p < 4; p++) {
                int R = row0 + wr + rt * 16 + lq * 4 + p;
                float v = acc[rt][ct][p] + bias;
                float e = __expf(2.f * v);          // tanh(v) = 1 - 2/(e^{2v}+1)
                out[(size_t)R * 1024 + n] = 1.f - 2.f / (e + 1.f);
            }
        }
    }
}

// ---------------------------------------------------------------------------
extern "C" void kernel_launch(void* const* d_in, const int* in_sizes, int n_in,
                              void* d_out, int out_size, void* d_ws, size_t ws_size,
                              hipStream_t stream)
{
    const void* x  = d_in[0];
    const void* Wr = d_in[1];
    const void* br = d_in[2];
    const void* Ww = d_in[3];
    const void* bw = d_in[4];
    const void* Wm = d_in[5];
    const void* bm = d_in[6];
    const void* Wp = d_in[7];
    const void* bp = d_in[8];
    const void* Wo = d_in[9];
    const void* bo = d_in[10];
    float* out = (float*)d_out;

    char* ws = (char*)d_ws;
    int* flag  = (int*)ws;                     // 4 B (pad to 1 KiB)
    u16* W3T   = (u16*)(ws + 1024);            //  96*1024*2  = 196608
    u16* WpT   = (u16*)(ws + 197632);          //  1024*32*2  = 65536
    u16* WoT   = (u16*)(ws + 263168);          //  1024*2048*2= 4194304
    u16* biasp = (u16*)(ws + 4457472);         //  2144*2 -> pad 8192
    u16* gates = (u16*)(ws + 4465664);         //  32768*96*2 = 6291456
    u16* rm    = (u16*)(ws + 10757120);        //  32768*32*2 = 2097152
    u16* q     = (u16*)(ws + 12854272);        //  32768*1024*2 = 67108864
                                               //  total: 79963136 B

    zej_detect<<<1, 64, 0, stream>>>((const unsigned int*)x, flag);
    zej_pack<<<8713, 256, 0, stream>>>(Wr, Ww, Wm, Wp, Wo, br, bw, bm, bp, bo,
                                       W3T, WpT, WoT, biasp, flag);
    zej_gates<<<BS_TOT / 128, 256, 0, stream>>>(x, W3T, biasp, gates, flag);
    zej_scan<<<256, 64, 0, stream>>>(gates, rm);
    zej_q<<<dim3(BS_TOT / 64, 4), 256, 0, stream>>>(rm, WpT, biasp, q);
    zej_out<<<dim3(BS_TOT / 128, 8), 256, 0, stream>>>(x, q, WoT, biasp, out, flag);
}